// Round 7
// baseline (210.342 us; speedup 1.0000x reference)
//
#include <hip/hip_runtime.h>
#include <hip/hip_bf16.h>

typedef __attribute__((ext_vector_type(8))) short short8;
typedef __attribute__((ext_vector_type(4))) short short4v;
typedef __attribute__((ext_vector_type(4))) float floatx4;

constexpr int B = 4, L = 2048, H = 16, E = 64, D = 1024;
constexpr int STR = 72;   // prep LDS transpose stride (144 B rows, 16B-aligned)
constexpr float SCL_LOG2E = 0.125f * 1.4426950408889634f;  // 1/sqrt(64) * log2(e)

__device__ __forceinline__ short bf16_bits(float x) {
    __hip_bfloat16 b = __float2bfloat16(x);
    return *(const short*)&b;
}

__device__ __forceinline__ short8 packq8(float4 a, float4 c, float scl) {
    short8 r;
    r[0] = bf16_bits(a.x * scl); r[1] = bf16_bits(a.y * scl);
    r[2] = bf16_bits(a.z * scl); r[3] = bf16_bits(a.w * scl);
    r[4] = bf16_bits(c.x * scl); r[5] = bf16_bits(c.y * scl);
    r[6] = bf16_bits(c.z * scl); r[7] = bf16_bits(c.w * scl);
    return r;
}

// Concatenate two P chunk fragments into one K=32 A-operand.
// k-order: k=quad*8+j -> s = (j>>2)*16 + quad*4 + (j&3); Vt uses the same map.
__device__ __forceinline__ short8 cat4(short4v a, short4v b) {
    short8 r;
    r[0] = a[0]; r[1] = a[1]; r[2] = a[2]; r[3] = a[3];
    r[4] = b[0]; r[5] = b[1]; r[6] = b[2]; r[7] = b[3];
    return r;
}

__device__ __forceinline__ short8 as8(uint4 u) {
    union { uint4 a; short8 b; } c; c.a = u; return c.b;
}

// ---------------------------------------------------------------------------
// Prep (UNCHANGED from R6): emit K and V^T per 64-s tile in MFMA-fragment
// order; all main-kernel fragment reads become lane-linear 16B chunks.
// K tile (8KB): chunk f = (nt*2+h)*64 + lane holds K[s=nt*16+c16][d=h*32+quad*8..+8)
// V tile (8KB): chunk g = (sp*4+dt)*64 + lane holds V[s_map(sp,quad,j)][dt*16+c16]
// ---------------------------------------------------------------------------
__global__ __launch_bounds__(256)
void prep_kv(const float* __restrict__ K, const float* __restrict__ V,
             short* __restrict__ Kb, short* __restrict__ Vt)
{
    __shared__ __align__(16) short vt[64 * STR];
    const int tid = threadIdx.x;
    const int bh = blockIdx.x >> 5, kt = blockIdx.x & 31;
    const int b = bh >> 4, h = bh & 15;

    const float* Kp = K + ((size_t)(b * L + kt * 64)) * D + h * E;
    const float* Vp = V + ((size_t)(b * L + kt * 64)) * D + h * E;
    short* Kop = Kb + ((size_t)(bh * 32 + kt)) * 4096;
    short* Vop = Vt + ((size_t)(bh * 32 + kt)) * 4096;

    // ---- K: global fp32 -> bf16, fragment-ordered 16B chunks ----
    #pragma unroll
    for (int it = 0; it < 2; ++it) {
        int f = it * 256 + tid;
        int nt = f >> 7, hh = (f >> 6) & 1, qd = (f >> 4) & 3, cc = f & 15;
        int s = nt * 16 + cc, d0 = hh * 32 + qd * 8;
        const float* p = Kp + (size_t)s * D + d0;
        float4 x = *(const float4*)p;
        float4 y = *(const float4*)(p + 4);
        union { short sh[8]; uint4 u; } pk;
        pk.sh[0] = bf16_bits(x.x); pk.sh[1] = bf16_bits(x.y);
        pk.sh[2] = bf16_bits(x.z); pk.sh[3] = bf16_bits(x.w);
        pk.sh[4] = bf16_bits(y.x); pk.sh[5] = bf16_bits(y.y);
        pk.sh[6] = bf16_bits(y.z); pk.sh[7] = bf16_bits(y.w);
        *(uint4*)(Kop + (size_t)f * 8) = pk.u;
    }

    // ---- V phase 1: transpose into LDS vt[d][s] ----
    #pragma unroll
    for (int p = 0; p < 4; ++p) {
        int idx = p * 256 + tid;
        int s = idx >> 4, c4 = (idx & 15) * 4;
        float4 g = *(const float4*)(Vp + (size_t)s * D + c4);
        vt[(c4 + 0) * STR + s] = bf16_bits(g.x);
        vt[(c4 + 1) * STR + s] = bf16_bits(g.y);
        vt[(c4 + 2) * STR + s] = bf16_bits(g.z);
        vt[(c4 + 3) * STR + s] = bf16_bits(g.w);
    }
    __syncthreads();

    // ---- V phase 2: K=32 B-operand order (two contiguous 4-s runs) ----
    #pragma unroll
    for (int it = 0; it < 2; ++it) {
        int f16 = it * 256 + tid;
        int sp = f16 >> 8, dt = (f16 >> 6) & 3, qd = (f16 >> 4) & 3, cc = f16 & 15;
        int d = dt * 16 + cc;
        int s0 = sp * 32 + qd * 4;
        uint2 lo = *(const uint2*)&vt[d * STR + s0];        // s0 .. s0+3
        uint2 hi = *(const uint2*)&vt[d * STR + s0 + 16];   // s0+16 .. s0+19
        uint4 u; u.x = lo.x; u.y = lo.y; u.z = hi.x; u.w = hi.y;
        *(uint4*)(Vop + (size_t)f16 * 8) = u;
    }
}

// ---------------------------------------------------------------------------
// Register tile: one 32-wide k-step of K and V fragments (8 x 16B/lane).
// K order j = 2*nt + h (nt = 16-chunk, h = d-half); V order j = dt.
// ---------------------------------------------------------------------------
struct KV { uint4 k[4]; uint4 v[4]; };

__device__ __forceinline__ KV load_tile(const short* __restrict__ Kt,
                                        const short* __restrict__ Vl, int t)
{
    KV r;
    const short* kp = Kt + (size_t)t * 2048;
    const short* vp = Vl + (size_t)t * 2048;
    #pragma unroll
    for (int j = 0; j < 4; ++j) {
        r.k[j] = *(const uint4*)(kp + j * 512);
        r.v[j] = *(const uint4*)(vp + j * 512);
    }
    return r;
}

// QK^T for one 16-s chunk (full) -> exp2 -> P fragment. acc has scale folded.
__device__ __forceinline__ void qkexp(short8 k0, short8 k1, short8 q0, short8 q1,
                                      float& l, short4v& p)
{
    floatx4 a = (floatx4){0.f, 0.f, 0.f, 0.f};
    a = __builtin_amdgcn_mfma_f32_16x16x32_bf16(k0, q0, a, 0, 0, 0);
    a = __builtin_amdgcn_mfma_f32_16x16x32_bf16(k1, q1, a, 0, 0, 0);
    #pragma unroll
    for (int r = 0; r < 4; ++r) {
        float e = __builtin_amdgcn_exp2f(a[r]);
        l += e;
        p[r] = bf16_bits(e);
    }
}

// Diagonal 16-chunk: chunk is row-aligned with the fragment, so the causal
// mask is the universal per-lane predicate  r > thr  (thr = c16 - 4*quad).
__device__ __forceinline__ void qkexp_diag(short8 k0, short8 k1, short8 q0, short8 q1,
                                           int thr, float& l, short4v& p)
{
    floatx4 a = (floatx4){0.f, 0.f, 0.f, 0.f};
    a = __builtin_amdgcn_mfma_f32_16x16x32_bf16(k0, q0, a, 0, 0, 0);
    a = __builtin_amdgcn_mfma_f32_16x16x32_bf16(k1, q1, a, 0, 0, 0);
    #pragma unroll
    for (int r = 0; r < 4; ++r) {
        float e = (r > thr) ? 0.f : __builtin_amdgcn_exp2f(a[r]);
        l += e;
        p[r] = bf16_bits(e);
    }
}

// Full interior step: 4 fragments (64 q-rows) share all K/V fragment regs.
__device__ __forceinline__ void step_full4(const KV& s, const short8 (&q)[4][2],
                                           floatx4 (&o)[4][4], float (&l)[4])
{
    const short8 k00 = as8(s.k[0]), k01 = as8(s.k[1]);
    const short8 k10 = as8(s.k[2]), k11 = as8(s.k[3]);
    #pragma unroll
    for (int f = 0; f < 4; ++f) {
        short4v p0, p1;
        qkexp(k00, k01, q[f][0], q[f][1], l[f], p0);
        qkexp(k10, k11, q[f][0], q[f][1], l[f], p1);
        const short8 pa = cat4(p0, p1);
        #pragma unroll
        for (int dt = 0; dt < 4; ++dt)
            o[f][dt] = __builtin_amdgcn_mfma_f32_16x16x32_bf16(pa, as8(s.v[dt]), o[f][dt], 0, 0, 0);
    }
}

// Tail steps (the 2 diagonal 32-wide tiles of each wave's range).
// TAIL 0 (t = 2qt):  f0 = diag c0 + zero c1; f1 = full c0 + diag c1; f2,f3 full.
// TAIL 1 (t = 2qt+1): f0,f1 skip; f2 = diag c0 + zero c1; f3 = full c0 + diag c1.
template<int TAIL>
__device__ __forceinline__ void step_tail(const KV& s, const short8 (&q)[4][2],
                                          floatx4 (&o)[4][4], float (&l)[4], int thr)
{
    const short8 k00 = as8(s.k[0]), k01 = as8(s.k[1]);
    const short8 k10 = as8(s.k[2]), k11 = as8(s.k[3]);
    #pragma unroll
    for (int f = 0; f < 4; ++f) {
        // role: 0 = diag c0 + zero c1; 1 = full c0 + diag c1; 2 = full; 3 = skip
        const int role = (TAIL == 0) ? ((f == 0) ? 0 : (f == 1) ? 1 : 2)
                                     : ((f < 2) ? 3 : (f == 2) ? 0 : 1);
        if (role == 3) continue;
        short4v p0, p1;
        if (role == 0) {
            qkexp_diag(k00, k01, q[f][0], q[f][1], thr, l[f], p0);
            p1 = (short4v){0, 0, 0, 0};
        } else if (role == 1) {
            qkexp(k00, k01, q[f][0], q[f][1], l[f], p0);
            qkexp_diag(k10, k11, q[f][0], q[f][1], thr, l[f], p1);
        } else {
            qkexp(k00, k01, q[f][0], q[f][1], l[f], p0);
            qkexp(k10, k11, q[f][0], q[f][1], l[f], p1);
        }
        const short8 pa = cat4(p0, p1);
        #pragma unroll
        for (int dt = 0; dt < 4; ++dt)
            o[f][dt] = __builtin_amdgcn_mfma_f32_16x16x32_bf16(pa, as8(s.v[dt]), o[f][dt], 0, 0, 0);
    }
}

__device__ __forceinline__ void store_frag(
    float lsum, const floatx4 (&o)[4], float* __restrict__ Op,
    int row_base, int c16, int quad)
{
    lsum += __shfl_xor(lsum, 16);
    lsum += __shfl_xor(lsum, 32);
    const int row0 = row_base + quad * 4;
    #pragma unroll
    for (int r = 0; r < 4; ++r) {
        const float inv = 1.f / __shfl(lsum, quad * 4 + r);  // l lives at lane c16==row
        #pragma unroll
        for (int dt = 0; dt < 4; ++dt)
            Op[(size_t)(row0 + r) * D + dt * 16 + c16] = o[dt][r] * inv;
    }
}

// ---------------------------------------------------------------------------
// Main: 2048 blocks x 64 threads (ONE wave per block, 64 q-rows via 4
// 16-row fragments sharing every K/V fragment load). NO LDS, NO BARRIERS:
// K/V fragments are loaded global->register (fragment-ordered workspace
// makes every read a perfectly coalesced lane-linear 16B chunk), double-
// buffered across the k-loop; the compiler emits counted vmcnt waits.
// KV stays L2-resident (512 KB/bh; 8 bh per XCD = 4 MB = L2).
//
// Grid mapping: xcd = i&7, bh = bits[5:3]<<3 | bits[2:0] (same-bh blocks on
// one XCD); qt = 4u + (u&1 ? 3-w : w) with u=(i>>8)&7, w=(i>>6)&3 -> every
// CU's 8 co-resident blocks sum to EXACTLY 264 k-steps (per-CU balanced
// through the 256-stride block->CU placement; R5 lesson re-derived).
// ---------------------------------------------------------------------------
__global__ __launch_bounds__(64, 2)
void attn_fwd_p(const float* __restrict__ Q, const short* __restrict__ Kb,
                const short* __restrict__ Vt, float* __restrict__ O)
{
    const int lane = threadIdx.x;       // 0..63
    const int c16  = lane & 15;
    const int quad = lane >> 4;

    const int i  = (int)blockIdx.x;
    const int bh = (((i >> 3) & 7) << 3) | (i & 7);
    const int w  = (i >> 6) & 3;
    const int u  = (i >> 8) & 7;
    const int qt = 4 * u + ((u & 1) ? (3 - w) : w);   // 0..31 (64-row q-tile)
    const int b  = bh >> 4;
    const int h  = bh & 15;

    const float* Qp = Q + ((size_t)b * L) * D + h * E;
    const short* Kt = Kb + ((size_t)bh * 32) * 4096 + lane * 8;
    const short* Vl = Vt + ((size_t)bh * 32) * 4096 + lane * 8;
    float*       Op = O + ((size_t)b * L) * D + h * E;

    const int m0  = qt * 64;            // first q-row; frag f at m0 + 16f
    const int thr = c16 - quad * 4;     // universal diag predicate

    // ---- Q fragments straight from global fp32 (scale*log2e folded) ----
    short8 q[4][2];
    #pragma unroll
    for (int f = 0; f < 4; ++f) {
        const float* qr = Qp + (size_t)(m0 + 16 * f + c16) * D + quad * 8;
        q[f][0] = packq8(*(const float4*)(qr),      *(const float4*)(qr + 4),  SCL_LOG2E);
        q[f][1] = packq8(*(const float4*)(qr + 32), *(const float4*)(qr + 36), SCL_LOG2E);
    }

    floatx4 o[4][4];
    #pragma unroll
    for (int f = 0; f < 4; ++f) {
        #pragma unroll
        for (int dt = 0; dt < 4; ++dt) o[f][dt] = (floatx4){0.f, 0.f, 0.f, 0.f};
    }
    float l[4] = {0.f, 0.f, 0.f, 0.f};

    const int nfull = 2 * qt;           // interior 32-wide k-tiles (even)

    KV A = load_tile(Kt, Vl, 0);
    KV Bv;
    for (int t = 0; t < nfull; t += 2) {
        Bv = load_tile(Kt, Vl, t + 1);          // prefetch lands under step(A)
        __builtin_amdgcn_s_setprio(1);
        step_full4(A, q, o, l);
        __builtin_amdgcn_s_setprio(0);
        A = load_tile(Kt, Vl, t + 2);           // t+2 <= nfull, always valid
        __builtin_amdgcn_s_setprio(1);
        step_full4(Bv, q, o, l);
        __builtin_amdgcn_s_setprio(0);
    }
    // diagonal pair: tiles nfull (in A) and nfull+1
    Bv = load_tile(Kt, Vl, nfull + 1);
    __builtin_amdgcn_s_setprio(1);
    step_tail<0>(A,  q, o, l, thr);
    step_tail<1>(Bv, q, o, l, thr);
    __builtin_amdgcn_s_setprio(0);

    #pragma unroll
    for (int f = 0; f < 4; ++f)
        store_frag(l[f], o[f], Op, m0 + 16 * f, c16, quad);
}

// ---------------------------------------------------------------------------
// Fallback (R2 kernel, proven): used only if ws_size < 32 MB
// ---------------------------------------------------------------------------
__global__ __launch_bounds__(256, 2)
void attn_fwd_fb(const float* __restrict__ Q, const float* __restrict__ K,
                 const float* __restrict__ V, float* __restrict__ O)
{
    constexpr int FSTR = 72;
    constexpr int FQT = 64;
    __shared__ __align__(16) short q_s[FQT * FSTR];
    __shared__ __align__(16) short k_s[64 * FSTR];
    __shared__ __align__(16) short vt_s[E * FSTR];
    __shared__ __align__(16) short p_s[4][16 * FSTR];

    const int tid  = threadIdx.x;
    const int wave = tid >> 6;
    const int lane = tid & 63;
    const int c16  = lane & 15;
    const int quad = lane >> 4;

    const int nqt = L / FQT;
    const int qt  = (nqt - 1) - (int)(blockIdx.x % nqt);
    const int bh  = blockIdx.x / nqt;
    const int b   = bh >> 4;
    const int h   = bh & 15;
    const int q_base = qt * FQT;

    const float* Qp = Q + ((size_t)b * L) * D + h * E;
    const float* Kp = K + ((size_t)b * L) * D + h * E;
    const float* Vp = V + ((size_t)b * L) * D + h * E;
    float*       Op = O + ((size_t)b * L) * D + h * E;

    #pragma unroll
    for (int p = 0; p < 4; ++p) {
        int idx = p * 256 + tid;
        int r = idx >> 4, c4 = (idx & 15) * 4;
        float4 f = *(const float4*)(Qp + (size_t)(q_base + r) * D + c4);
        union { short s[4]; uint2 u; } pk;
        pk.s[0] = bf16_bits(f.x); pk.s[1] = bf16_bits(f.y);
        pk.s[2] = bf16_bits(f.z); pk.s[3] = bf16_bits(f.w);
        *(uint2*)&q_s[r * FSTR + c4] = pk.u;
    }
    __syncthreads();

    short8 qf0 = *(const short8*)&q_s[(wave * 16 + c16) * FSTR + quad * 8];
    short8 qf1 = *(const short8*)&q_s[(wave * 16 + c16) * FSTR + 32 + quad * 8];

    floatx4 o_acc[4];
    #pragma unroll
    for (int nt = 0; nt < 4; ++nt) o_acc[nt] = (floatx4){0.f, 0.f, 0.f, 0.f};
    float m_run[4], l_run[4];
    #pragma unroll
    for (int r = 0; r < 4; ++r) { m_run[r] = -__builtin_inff(); l_run[r] = 0.f; }

    for (int t = 0; t <= qt; ++t) {
        const int k_base = t * 64;
        __syncthreads();
        #pragma unroll
        for (int p = 0; p < 4; ++p) {
            int idx = p * 256 + tid;
            int r = idx >> 4, c4 = (idx & 15) * 4;
            float4 f = *(const float4*)(Kp + (size_t)(k_base + r) * D + c4);
            union { short s[4]; uint2 u; } pk;
            pk.s[0] = bf16_bits(f.x); pk.s[1] = bf16_bits(f.y);
            pk.s[2] = bf16_bits(f.z); pk.s[3] = bf16_bits(f.w);
            *(uint2*)&k_s[r * FSTR + c4] = pk.u;
        }
        #pragma unroll
        for (int p = 0; p < 4; ++p) {
            int s  = lane;
            int dg = p * 4 + wave;
            float4 f = *(const float4*)(Vp + (size_t)(k_base + s) * D + dg * 4);
            vt_s[(dg * 4 + 0) * FSTR + s] = bf16_bits(f.x);
            vt_s[(dg * 4 + 1) * FSTR + s] = bf16_bits(f.y);
            vt_s[(dg * 4 + 2) * FSTR + s] = bf16_bits(f.z);
            vt_s[(dg * 4 + 3) * FSTR + s] = bf16_bits(f.w);
        }
        __syncthreads();

        floatx4 sc[4];
        #pragma unroll
        for (int nt = 0; nt < 4; ++nt) {
            floatx4 acc = (floatx4){0.f, 0.f, 0.f, 0.f};
            short8 b0 = *(const short8*)&k_s[(nt * 16 + c16) * FSTR + quad * 8];
            short8 b1 = *(const short8*)&k_s[(nt * 16 + c16) * FSTR + 32 + quad * 8];
            acc = __builtin_amdgcn_mfma_f32_16x16x32_bf16(qf0, b0, acc, 0, 0, 0);
            acc = __builtin_amdgcn_mfma_f32_16x16x32_bf16(qf1, b1, acc, 0, 0, 0);
            sc[nt] = acc;
        }

        const int q_row0 = q_base + wave * 16 + quad * 4;
        #pragma unroll
        for (int nt = 0; nt < 4; ++nt) {
            const int k_col = k_base + nt * 16 + c16;
            #pragma unroll
            for (int r = 0; r < 4; ++r) {
                float s = sc[nt][r] * SCL_LOG2E;
                sc[nt][r] = (k_col <= q_row0 + r) ? s : -__builtin_inff();
            }
        }

        float alpha[4];
        #pragma unroll
        for (int r = 0; r < 4; ++r) {
            float mx = fmaxf(fmaxf(sc[0][r], sc[1][r]), fmaxf(sc[2][r], sc[3][r]));
            mx = fmaxf(mx, __shfl_xor(mx, 1));
            mx = fmaxf(mx, __shfl_xor(mx, 2));
            mx = fmaxf(mx, __shfl_xor(mx, 4));
            mx = fmaxf(mx, __shfl_xor(mx, 8));
            const float m_new = fmaxf(m_run[r], mx);
            alpha[r] = exp2f(m_run[r] - m_new);
            m_run[r] = m_new;
        }
        float psum[4] = {0.f, 0.f, 0.f, 0.f};
        #pragma unroll
        for (int nt = 0; nt < 4; ++nt) {
            #pragma unroll
            for (int r = 0; r < 4; ++r) {
                float p = exp2f(sc[nt][r] - m_run[r]);
                sc[nt][r] = p;
                psum[r] += p;
            }
        }
        #pragma unroll
        for (int r = 0; r < 4; ++r) {
            float s = psum[r];
            s += __shfl_xor(s, 1);
            s += __shfl_xor(s, 2);
            s += __shfl_xor(s, 4);
            s += __shfl_xor(s, 8);
            l_run[r] = l_run[r] * alpha[r] + s;
            #pragma unroll
            for (int nt = 0; nt < 4; ++nt) o_acc[nt][r] *= alpha[r];
        }

        short* pw = &p_s[wave][0];
        #pragma unroll
        for (int nt = 0; nt < 4; ++nt) {
            #pragma unroll
            for (int r = 0; r < 4; ++r)
                pw[(quad * 4 + r) * FSTR + nt * 16 + c16] = bf16_bits(sc[nt][r]);
        }
        __syncthreads();

        #pragma unroll
        for (int kc = 0; kc < 2; ++kc) {
            short8 pa = *(const short8*)&pw[c16 * FSTR + kc * 32 + quad * 8];
            #pragma unroll
            for (int nt = 0; nt < 4; ++nt) {
                short8 vb = *(const short8*)&vt_s[(nt * 16 + c16) * FSTR + kc * 32 + quad * 8];
                o_acc[nt] = __builtin_amdgcn_mfma_f32_16x16x32_bf16(pa, vb, o_acc[nt], 0, 0, 0);
            }
        }
    }

    const int q_row0 = q_base + wave * 16 + quad * 4;
    #pragma unroll
    for (int r = 0; r < 4; ++r) {
        const float inv_l = 1.f / l_run[r];
        #pragma unroll
        for (int nt = 0; nt < 4; ++nt)
            Op[(size_t)(q_row0 + r) * D + nt * 16 + c16] = o_acc[nt][r] * inv_l;
    }
}

extern "C" void kernel_launch(void* const* d_in, const int* in_sizes, int n_in,
                              void* d_out, int out_size, void* d_ws, size_t ws_size,
                              hipStream_t stream)
{
    const float* Q = (const float*)d_in[0];
    const float* K = (const float*)d_in[1];
    const float* V = (const float*)d_in[2];
    float* O = (float*)d_out;

    const size_t elems = (size_t)B * H * L * E;          // 8M per tensor
    const size_t need  = 2 * elems * sizeof(short);      // 32 MiB

    if (ws_size >= need) {
        short* Kb = (short*)d_ws;
        short* Vt = Kb + elems;
        prep_kv<<<dim3(B * H * 32), dim3(256), 0, stream>>>(K, V, Kb, Vt);
        attn_fwd_p<<<dim3(2048), dim3(64), 0, stream>>>(Q, Kb, Vt, O);
    } else {
        attn_fwd_fb<<<dim3(B * H * (L / 64)), dim3(256), 0, stream>>>(Q, K, V, O);
    }
}